// Round 14
// baseline (194.381 us; speedup 1.0000x reference)
//
#include <hip/hip_runtime.h>
#include <hip/hip_fp16.h>
#include <math.h>

#define CAP 48       // max bucketed in-degree; Poisson(16), P(deg>=48) ~ 8e-11/node
#define PARTBITS 8   // 256 dsts per bin
#define BINW 256
#define NB 240       // routing blocks (phase A)
#define SEGCAP 48    // per-(bin,block) queue segment; mean 17, 7.5 sigma

typedef float f32x4 __attribute__((ext_vector_type(4)));
typedef __bf16 bf16x8 __attribute__((ext_vector_type(8)));
typedef unsigned short ushort8 __attribute__((ext_vector_type(8)));
typedef int i32x4 __attribute__((ext_vector_type(4)));
typedef int i32x2 __attribute__((ext_vector_type(2)));

__device__ __forceinline__ float leaky(float x){ return x > 0.f ? x : 0.2f * x; }
__device__ __forceinline__ float eluf(float x){ return x > 0.f ? x : __expf(x) - 1.f; }
__device__ __forceinline__ unsigned short f2bf(float f){  // RNE float->bf16
  unsigned u = __float_as_uint(f);
  u += 0x7FFF + ((u >> 16) & 1);
  return (unsigned short)(u >> 16);
}
__device__ __forceinline__ float bf2f(unsigned short u){
  return __uint_as_float(((unsigned)u) << 16);
}
__device__ __forceinline__ unsigned short f2h(float f){
  return __half_as_ushort(__float2half(f));
}
__device__ __forceinline__ float h2f(unsigned short u){
  return __half2float(__ushort_as_half(u));
}

// K1: compute vw in LDS, emit COMPACT 32B node record (R12 WIN):
//   v0 = {x0..x5 bf16, as0,as1 fp16}; v1 = {as2,as3, ad0..ad3 fp16, 0,0}
// Also pre-pack W2 into bf16 MFMA B-fragment lane order; zero gtail.
__global__ __launch_bounds__(256) void k1_att1(const float* __restrict__ x,
    const float* __restrict__ W1, const float* __restrict__ as1,
    const float* __restrict__ ad1, const float* __restrict__ W2,
    unsigned short* __restrict__ Bfrag, ushort8* __restrict__ rec8,
    int* __restrict__ gtail, int N){
  __shared__ float vw[48];
  int t = threadIdx.x;
  int gid = blockIdx.x * 256 + t;
  if (gid == 0) *gtail = 0;   // CSR allocator, consumed by k2b (stream-ordered)
  if (gid < 16384){
    int j  = gid & 7;
    int L  = (gid >> 3) & 63;
    int ct = (gid >> 9) & 3;
    int ks = gid >> 11;
    int k = ks*32 + ((L >> 4) & 3)*8 + j;
    int c = ct*16 + (L & 15);
    Bfrag[gid] = f2bf(W2[k*64 + c]);
  }
  if (t < 48){
    int side = t / 24, r = t % 24, f = r / 4, h = r % 4;
    const float* att = side ? ad1 : as1;
    float s = 0.f;
    for (int c = 0; c < 64; ++c) s += W1[f*256 + h*64 + c] * att[h*64 + c];
    vw[side*24 + f*4 + h] = s;
  }
  __syncthreads();
  int n = gid;
  if (n >= N) return;
  float xf[6];
  for (int f = 0; f < 6; ++f) xf[f] = x[n*6 + f];
  float as[4], ad[4];
  for (int h = 0; h < 4; ++h){
    float s = 0.f, d = 0.f;
    for (int f = 0; f < 6; ++f){ s += xf[f] * vw[f*4 + h]; d += xf[f] * vw[24 + f*4 + h]; }
    as[h] = s; ad[h] = d;
  }
  ushort8 v0, v1;
  v0[0]=f2bf(xf[0]); v0[1]=f2bf(xf[1]); v0[2]=f2bf(xf[2]); v0[3]=f2bf(xf[3]);
  v0[4]=f2bf(xf[4]); v0[5]=f2bf(xf[5]); v0[6]=f2h(as[0]); v0[7]=f2h(as[1]);
  v1[0]=f2h(as[2]); v1[1]=f2h(as[3]); v1[2]=f2h(ad[0]); v1[3]=f2h(ad[1]);
  v1[4]=f2h(ad[2]); v1[5]=f2h(ad[3]); v1[6]=0; v1[7]=0;
  rec8[n*2 + 0] = v0;
  rec8[n*2 + 1] = v1;
}

// K2a: route edges into per-(bin,block) queue segments; ranks from block-local
// LDS counters — zero global atomics. EXACT R9 version (replay-check proven).
__global__ __launch_bounds__(256) void k2a_route(const int* __restrict__ ei,
    int E, int NR, i32x2* __restrict__ queue, int* __restrict__ qcnt){
  __shared__ int lcnt[512];
  int t = threadIdx.x, blk = blockIdx.x;
  for (int i = t; i < NR; i += 256) lcnt[i] = 0;
  __syncthreads();
  int E4 = E >> 2;
  const i32x4* s4 = (const i32x4*)ei;
  const i32x4* d4 = (const i32x4*)(ei + E);
  for (int i = blk*256 + t; i < E4; i += NB*256){
    i32x4 s = __builtin_nontemporal_load(s4 + i);
    i32x4 d = __builtin_nontemporal_load(d4 + i);
    #pragma unroll
    for (int j = 0; j < 4; ++j){
      int p = d[j] >> PARTBITS;
      int r = atomicAdd(&lcnt[p], 1);
      if (r < SEGCAP){ i32x2 v = {d[j], s[j]}; queue[((size_t)p*NB + blk)*SEGCAP + r] = v; }
    }
  }
  if (blk == 0 && t < (E & 3)){
    int e = E4*4 + t;
    int dd = ei[E + e], ss = ei[e];
    int p = dd >> PARTBITS;
    int r = atomicAdd(&lcnt[p], 1);
    if (r < SEGCAP){ i32x2 v = {dd, ss}; queue[((size_t)p*NB + blk)*SEGCAP + r] = v; }
  }
  __syncthreads();
  for (int i = t; i < NR; i += 256) qcnt[(size_t)i*NB + blk] = lcnt[i];
}

// K2b (compacted): one block per bin (256 dsts).
// R13 waste audit: full padded queue scan read 36MB (12.8 valid) and the
// CAP-padded bucket wrote 19.6MB (6.4 valid). Fix: (1) prefix-scan the 240
// segment counts, iterate only the V valid entries (binary search over the
// segment prefix); (2) CSR-compact bucket: node prefix scan in-bin, one
// atomicAdd(gtail) per bin for the base, fully-coalesced dense write-out +
// row_start[n]. Content per node identical (order within row arbitrary, as
// before — aggregation is order-independent up to fp rounding).
__global__ __launch_bounds__(1024) void k2b_build(const i32x2* __restrict__ queue,
    const int* __restrict__ qcnt, int* __restrict__ cnt,
    int* __restrict__ row_start, int* __restrict__ bucket,
    int* __restrict__ gtail){
  __shared__ int lc[BINW];
  __shared__ int lq[NB];
  __shared__ int spref[NB];
  __shared__ int npref[BINW+1];
  __shared__ int scan[BINW];
  __shared__ int lbuck[BINW*CAP];   // 48KB
  __shared__ int gbase_s;
  int t = threadIdx.x, bin = blockIdx.x;
  if (t < BINW) lc[t] = 0;
  for (int i = t; i < NB; i += 1024) lq[i] = min(qcnt[(size_t)bin*NB + i], SEGCAP);
  __syncthreads();
  // exclusive prefix over segment counts (Hillis-Steele on 256-padded array)
  if (t < 256) scan[t] = (t < NB) ? lq[t] : 0;
  __syncthreads();
  for (int off = 1; off < 256; off <<= 1){
    int v = 0;
    if (t < 256 && t >= off) v = scan[t - off];
    __syncthreads();
    if (t < 256) scan[t] += v;
    __syncthreads();
  }
  if (t < NB) spref[t] = (t == 0) ? 0 : scan[t-1];
  int V = scan[NB-1];               // valid entries in this bin's queue
  __syncthreads();
  // compact scatter: only valid entries touched
  const i32x2* q = queue + (size_t)bin*NB*SEGCAP;
  for (int vi = t; vi < V; vi += 1024){
    int lo = 0, hi = NB-1;          // largest b with spref[b] <= vi
    while (lo < hi){ int mid = (lo+hi+1) >> 1; if (spref[mid] <= vi) lo = mid; else hi = mid-1; }
    i32x2 pr = q[lo*SEGCAP + (vi - spref[lo])];
    int ld = pr.x & (BINW-1);
    int pos = atomicAdd(&lc[ld], 1);
    if (pos < CAP) lbuck[ld*CAP + pos] = pr.y;
  }
  __syncthreads();
  // capped node counts -> exclusive prefix
  if (t < 256) scan[t] = min(lc[t], CAP);
  __syncthreads();
  for (int off = 1; off < 256; off <<= 1){
    int v = 0;
    if (t < 256 && t >= off) v = scan[t - off];
    __syncthreads();
    if (t < 256) scan[t] += v;
    __syncthreads();
  }
  if (t < 256) npref[t] = (t == 0) ? 0 : scan[t-1];
  if (t == 0){
    npref[BINW] = scan[BINW-1];
    gbase_s = atomicAdd(gtail, scan[BINW-1]);
  }
  __syncthreads();
  int gbase = gbase_s;
  int Vn = npref[BINW];
  // dense, coalesced CSR write-out
  for (int vi = t; vi < Vn; vi += 1024){
    int lo = 0, hi = BINW-1;        // largest node with npref[node] <= vi
    while (lo < hi){ int mid = (lo+hi+1) >> 1; if (npref[mid] <= vi) lo = mid; else hi = mid-1; }
    bucket[gbase + vi] = lbuck[lo*CAP + (vi - npref[lo])];
  }
  if (t < BINW){
    cnt[bin*BINW + t] = min(lc[t], CAP);
    row_start[bin*BINW + t] = gbase + npref[t];
  }
}

// K3: per-NODE layer-1 softmax-aggregate, all 4 heads, compact 32B gathers.
// R12 body; bucket now CSR (row_start + capped cnt).
__global__ __launch_bounds__(256) void k3_agg1(const ushort8* __restrict__ rec8,
    const int* __restrict__ cnt, const int* __restrict__ row_start,
    const int* __restrict__ bucket, float* __restrict__ aggr, int N){
  int n = blockIdx.x * 256 + threadIdx.x;
  if (n >= N) return;
  ushort8 v0 = rec8[n*2+0], v1 = rec8[n*2+1];
  float xf[6] = {bf2f(v0[0]), bf2f(v0[1]), bf2f(v0[2]), bf2f(v0[3]), bf2f(v0[4]), bf2f(v0[5])};
  float as[4] = {h2f(v0[6]), h2f(v0[7]), h2f(v1[0]), h2f(v1[1])};
  float ad[4] = {h2f(v1[2]), h2f(v1[3]), h2f(v1[4]), h2f(v1[5])};
  float acc[4][6], den[4];
  for (int h = 0; h < 4; ++h){
    float e0 = __expf(leaky(as[h] + ad[h]));   // self-loop
    den[h] = e0;
    for (int f = 0; f < 6; ++f) acc[h][f] = e0 * xf[f];
  }
  int deg = cnt[n];
  const int* bk = bucket + row_start[n];
  int i = 0;
  for (; i + 4 <= deg; i += 4){
    int sid[4];
    #pragma unroll
    for (int j = 0; j < 4; ++j) sid[j] = bk[i+j];
    ushort8 ra[4], rb[4];
    #pragma unroll
    for (int j = 0; j < 4; ++j){
      ra[j] = rec8[sid[j]*2+0]; rb[j] = rec8[sid[j]*2+1];
    }
    #pragma unroll
    for (int j = 0; j < 4; ++j){
      float sx[6] = {bf2f(ra[j][0]), bf2f(ra[j][1]), bf2f(ra[j][2]),
                     bf2f(ra[j][3]), bf2f(ra[j][4]), bf2f(ra[j][5])};
      float sa[4] = {h2f(ra[j][6]), h2f(ra[j][7]), h2f(rb[j][0]), h2f(rb[j][1])};
      #pragma unroll
      for (int h = 0; h < 4; ++h){
        float e = __expf(leaky(sa[h] + ad[h]));
        den[h] += e;
        #pragma unroll
        for (int f = 0; f < 6; ++f) acc[h][f] += e * sx[f];
      }
    }
  }
  for (; i < deg; ++i){
    int s = bk[i];
    ushort8 a0 = rec8[s*2+0], a1 = rec8[s*2+1];
    float sx[6] = {bf2f(a0[0]), bf2f(a0[1]), bf2f(a0[2]), bf2f(a0[3]), bf2f(a0[4]), bf2f(a0[5])};
    float sa[4] = {h2f(a0[6]), h2f(a0[7]), h2f(a1[0]), h2f(a1[1])};
    for (int h = 0; h < 4; ++h){
      float e = __expf(leaky(sa[h] + ad[h]));
      den[h] += e;
      for (int f = 0; f < 6; ++f) acc[h][f] += e * sx[f];
    }
  }
  float4* o = (float4*)(aggr + (size_t)n*32);
  o[0] = make_float4(acc[0][0], acc[0][1], acc[0][2], acc[0][3]);
  o[1] = make_float4(acc[0][4], acc[0][5], acc[1][0], acc[1][1]);
  o[2] = make_float4(acc[1][2], acc[1][3], acc[1][4], acc[1][5]);
  o[3] = make_float4(acc[2][0], acc[2][1], acc[2][2], acc[2][3]);
  o[4] = make_float4(acc[2][4], acc[2][5], acc[3][0], acc[3][1]);
  o[5] = make_float4(acc[3][2], acc[3][3], acc[3][4], acc[3][5]);
  o[6] = make_float4(den[0], den[1], den[2], den[3]);
}

// K4 (MFMA + LDS staging): EXACT R13 version (42->sub-fill WIN).
__global__ __launch_bounds__(256) void k4_mfma(
    const float* __restrict__ aggr, const float* __restrict__ W1,
    const float* __restrict__ b1, const unsigned short* __restrict__ Bfrag,
    const float* __restrict__ as2v, const float* __restrict__ ad2v,
    unsigned short* __restrict__ h2h, float2* __restrict__ a2, int N){
  __shared__ float w1s[6*256];     // 6KB
  __shared__ float b1s[256];       // 1KB
  __shared__ ushort8 bfs[2048];    // 32KB
  int t = threadIdx.x;
  {
    const float4* w1g = (const float4*)W1;
    float4* w1l = (float4*)w1s;
    for (int i = t; i < 384; i += 256) w1l[i] = w1g[i];
    if (t < 64) ((float4*)b1s)[t] = ((const float4*)b1)[t];
    const ushort8* bfg = (const ushort8*)Bfrag;
    #pragma unroll
    for (int i = 0; i < 8; ++i) bfs[t + 256*i] = bfg[t + 256*i];
  }
  int L = t & 63;
  int w = t >> 6;
  int base = blockIdx.x * 64;
  int m = L & 15;
  int quad = L >> 4;
  int na = base + w*16 + m;
  int nc = min(na, N-1);
  const float4* A4 = (const float4*)(aggr + (size_t)nc*32);
  float4 q0=A4[0], q1=A4[1], q2=A4[2], q3=A4[3], q4=A4[4], q5=A4[5], q6=A4[6];
  float d0=1.f/q6.x, d1=1.f/q6.y, d2=1.f/q6.z, d3=1.f/q6.w;
  float af[24];
  af[0]=q0.x*d0;  af[1]=q0.y*d0;  af[2]=q0.z*d0;  af[3]=q0.w*d0;  af[4]=q1.x*d0;  af[5]=q1.y*d0;
  af[6]=q1.z*d1;  af[7]=q1.w*d1;  af[8]=q2.x*d1;  af[9]=q2.y*d1;  af[10]=q2.z*d1; af[11]=q2.w*d1;
  af[12]=q3.x*d2; af[13]=q3.y*d2; af[14]=q3.z*d2; af[15]=q3.w*d2; af[16]=q4.x*d2; af[17]=q4.y*d2;
  af[18]=q4.z*d3; af[19]=q4.w*d3; af[20]=q5.x*d3; af[21]=q5.y*d3; af[22]=q5.z*d3; af[23]=q5.w*d3;

  f32x4 acc[4];
  #pragma unroll
  for (int ct = 0; ct < 4; ++ct) acc[ct] = (f32x4){0.f, 0.f, 0.f, 0.f};
  __syncthreads();

  #pragma unroll
  for (int ks = 0; ks < 8; ++ks){
    int kb = ks*32 + quad*8;
    int kc = kb >> 6;
    const float* afk = af + kc*6;
    float4 bb0 = *(const float4*)(b1s + kb);
    float4 bb1 = *(const float4*)(b1s + kb + 4);
    float s0=bb0.x, s1=bb0.y, s2=bb0.z, s3=bb0.w;
    float s4=bb1.x, s5=bb1.y, s6=bb1.z, s7=bb1.w;
    #pragma unroll
    for (int f = 0; f < 6; ++f){
      float a = afk[f];
      float4 w0 = *(const float4*)(w1s + f*256 + kb);
      float4 w1 = *(const float4*)(w1s + f*256 + kb + 4);
      s0 += a*w0.x; s1 += a*w0.y; s2 += a*w0.z; s3 += a*w0.w;
      s4 += a*w1.x; s5 += a*w1.y; s6 += a*w1.z; s7 += a*w1.w;
    }
    ushort8 ap;
    ap[0]=f2bf(eluf(s0)); ap[1]=f2bf(eluf(s1)); ap[2]=f2bf(eluf(s2)); ap[3]=f2bf(eluf(s3));
    ap[4]=f2bf(eluf(s4)); ap[5]=f2bf(eluf(s5)); ap[6]=f2bf(eluf(s6)); ap[7]=f2bf(eluf(s7));
    bf16x8 av = __builtin_bit_cast(bf16x8, ap);
    #pragma unroll
    for (int ct = 0; ct < 4; ++ct){
      bf16x8 bv = __builtin_bit_cast(bf16x8, bfs[(ks*4 + ct)*64 + L]);
      acc[ct] = __builtin_amdgcn_mfma_f32_16x16x32_bf16(av, bv, acc[ct], 0, 0, 0);
    }
  }

  float asv[4], adv[4];
  #pragma unroll
  for (int ct = 0; ct < 4; ++ct){ asv[ct] = as2v[ct*16 + m]; adv[ct] = ad2v[ct*16 + m]; }
  float ps[4] = {0,0,0,0}, pd[4] = {0,0,0,0};
  #pragma unroll
  for (int ct = 0; ct < 4; ++ct)
    #pragma unroll
    for (int r = 0; r < 4; ++r){
      ps[r] += acc[ct][r] * asv[ct];
      pd[r] += acc[ct][r] * adv[ct];
    }
  #pragma unroll
  for (int r = 0; r < 4; ++r){
    int nr = base + w*16 + quad*4 + r;
    if (nr < N){
      #pragma unroll
      for (int ct = 0; ct < 4; ++ct)
        h2h[(size_t)nr*64 + ct*16 + m] = f2h(acc[ct][r]);
    }
  }
  #pragma unroll
  for (int mask = 1; mask <= 8; mask <<= 1){
    #pragma unroll
    for (int r = 0; r < 4; ++r){
      ps[r] += __shfl_xor(ps[r], mask, 64);
      pd[r] += __shfl_xor(pd[r], mask, 64);
    }
  }
  if (m == 0){
    #pragma unroll
    for (int r = 0; r < 4; ++r){
      int nr = base + w*16 + quad*4 + r;
      if (nr < N) a2[nr] = make_float2(ps[r], pd[r]);
    }
  }
}

// K5: layer-2 aggregation only for drone dsts (first ND) + elu + MLP head.
// fp16 h2 gathers; bucket now CSR.
__global__ __launch_bounds__(256) void k5_out(
    const unsigned short* __restrict__ h2h, const float2* __restrict__ a2,
    const int* __restrict__ cnt, const int* __restrict__ row_start,
    const int* __restrict__ bucket, const float* __restrict__ b2,
    const float* __restrict__ fc1w, const float* __restrict__ fc1b,
    const float* __restrict__ fc2w, const float* __restrict__ fc2b,
    float* __restrict__ out, int ND){
  __shared__ float hb[4][64];
  int lane = threadIdx.x & 63;
  int w = threadIdx.x >> 6;
  int n = blockIdx.x * 4 + w;
  if (n >= ND) return;
  float2 self = a2[n];
  float adv = self.y;
  float e0 = __expf(leaky(self.x + adv));
  float den = e0;
  float acc = e0 * h2f(h2h[(size_t)n*64 + lane]);
  int deg = cnt[n];
  const int* bk = bucket + row_start[n];
  int i = 0;
  for (; i + 4 <= deg; i += 4){
    int sid[4];
    #pragma unroll
    for (int j = 0; j < 4; ++j) sid[j] = bk[i+j];
    float av[4]; unsigned short hv4[4];
    #pragma unroll
    for (int j = 0; j < 4; ++j){
      av[j] = a2[sid[j]].x;
      hv4[j] = h2h[(size_t)sid[j]*64 + lane];
    }
    #pragma unroll
    for (int j = 0; j < 4; ++j){
      float e = __expf(leaky(av[j] + adv));
      den += e;
      acc += e * h2f(hv4[j]);
    }
  }
  for (; i < deg; ++i){
    int s = bk[i];
    float e = __expf(leaky(a2[s].x + adv));
    den += e;
    acc += e * h2f(h2h[(size_t)s*64 + lane]);
  }
  float hv = eluf(acc / den + b2[lane]);
  hb[w][lane] = hv;               // wave-local LDS (lockstep wave64)
  float t1 = fc1b[lane];
  for (int k = 0; k < 64; ++k) t1 += hb[w][k] * fc1w[k*64 + lane];
  t1 = fmaxf(t1, 0.f);
  float p0 = t1 * fc2w[lane*2 + 0];
  float p1 = t1 * fc2w[lane*2 + 1];
  for (int o = 32; o > 0; o >>= 1){
    p0 += __shfl_down(p0, o, 64);
    p1 += __shfl_down(p1, o, 64);
  }
  if (lane == 0){
    out[n*2 + 0] = tanhf(p0 + fc2b[0]) * 2.f;
    out[n*2 + 1] = tanhf(p1 + fc2b[1]) * 2.f;
  }
}

extern "C" void kernel_launch(void* const* d_in, const int* in_sizes, int n_in,
                              void* d_out, int out_size, void* d_ws, size_t ws_size,
                              hipStream_t stream){
  const float* x    = (const float*)d_in[0];
  const int*   ei   = (const int*)d_in[1];    // harness passes integers as int32
  const float* W1   = (const float*)d_in[3];
  const float* as1  = (const float*)d_in[4];
  const float* ad1  = (const float*)d_in[5];
  const float* b1   = (const float*)d_in[6];
  const float* W2   = (const float*)d_in[7];
  const float* as2  = (const float*)d_in[8];
  const float* ad2  = (const float*)d_in[9];
  const float* b2   = (const float*)d_in[10];
  const float* fc1w = (const float*)d_in[11];
  const float* fc1b = (const float*)d_in[12];
  const float* fc2w = (const float*)d_in[13];
  const float* fc2b = (const float*)d_in[14];
  float* out = (float*)d_out;

  int N  = in_sizes[0] / 6;
  int E  = in_sizes[1] / 2;
  int ND = out_size / 2;
  int NR = (N + BINW - 1) >> PARTBITS;   // number of dst bins

  char* p = (char*)d_ws;
  auto alloc = [&](size_t bytes){ void* r = (void*)p; p += (bytes + 255) & ~(size_t)255; return r; };
  int*            cnt    = (int*)           alloc((size_t)NR * BINW * 4);
  int*            rowst  = (int*)           alloc((size_t)NR * BINW * 4);
  int*            bucket = (int*)           alloc(((size_t)E + 1024) * 4);   // CSR: sum(min(deg,CAP)) <= E
  ushort8*        rec8   = (ushort8*)       alloc((size_t)N * 32);
  float*          aggr   = (float*)         alloc((size_t)N * 128);
  unsigned short* h2h    = (unsigned short*)alloc((size_t)N * 128);
  float2*         a2     = (float2*)        alloc((size_t)N * 8);
  unsigned short* Bfrag  = (unsigned short*)alloc(16384 * 2);
  i32x2*          queue  = (i32x2*)         alloc((size_t)NR * NB * SEGCAP * 8);
  int*            qcnt   = (int*)           alloc((size_t)NR * NB * 4);
  int*            gtail  = (int*)           alloc(256);

  size_t needed = (size_t)(p - (char*)d_ws);
  if (needed > ws_size) return;   // clean fail instead of GPU fault

  k1_att1<<<(N + 255)/256, 256, 0, stream>>>(x, W1, as1, ad1, W2, Bfrag, rec8, gtail, N);
  k2a_route<<<NB, 256, 0, stream>>>(ei, E, NR, queue, qcnt);
  k2b_build<<<NR, 1024, 0, stream>>>(queue, qcnt, cnt, rowst, bucket, gtail);
  k3_agg1<<<(N + 255)/256, 256, 0, stream>>>(rec8, cnt, rowst, bucket, aggr, N);
  k4_mfma<<<(N + 63)/64, 256, 0, stream>>>(aggr, W1, b1, Bfrag, as2, ad2, h2h, a2, N);
  k5_out<<<(ND + 3)/4, 256, 0, stream>>>(h2h, a2, cnt, rowst, bucket, b2,
                                         fc1w, fc1b, fc2w, fc2b, out, ND);
}

// Round 15
// 191.976 us; speedup vs baseline: 1.0125x; 1.0125x over previous
//
#include <hip/hip_runtime.h>
#include <hip/hip_fp16.h>
#include <math.h>

#define CAP 48       // max bucketed in-degree; Poisson(16), P(deg>=48) ~ 8e-11/node
#define PARTBITS 8   // 256 dsts per bin
#define BINW 256
#define NB 240       // routing blocks
#define SEGCAP 48    // per-(bin,block) queue segment; mean 17, 7.5 sigma

typedef float f32x4 __attribute__((ext_vector_type(4)));
typedef __bf16 bf16x8 __attribute__((ext_vector_type(8)));
typedef unsigned short ushort8 __attribute__((ext_vector_type(8)));
typedef unsigned short ushort4v __attribute__((ext_vector_type(4)));
typedef int i32x4 __attribute__((ext_vector_type(4)));
typedef int i32x2 __attribute__((ext_vector_type(2)));

__device__ __forceinline__ float leaky(float x){ return x > 0.f ? x : 0.2f * x; }
__device__ __forceinline__ float eluf(float x){ return x > 0.f ? x : __expf(x) - 1.f; }
__device__ __forceinline__ unsigned short f2bf(float f){  // RNE float->bf16
  unsigned u = __float_as_uint(f);
  u += 0x7FFF + ((u >> 16) & 1);
  return (unsigned short)(u >> 16);
}
__device__ __forceinline__ float bf2f(unsigned short u){
  return __uint_as_float(((unsigned)u) << 16);
}
__device__ __forceinline__ unsigned short f2h(float f){
  return __half_as_ushort(__float2half(f));
}
__device__ __forceinline__ float h2f(unsigned short u){
  return __half2float(__ushort_as_half(u));
}

// K12a: fused k1 (node records + Bfrag prepack) and k2a (edge routing) —
// independent work on disjoint block ranges, overlapped in one dispatch.
// Records (R15): recA[n]={x bf16 x6, as0,as1 fp16} 16B; recB[n]={x, as2,as3}
// 16B; recC[n]={ad0..ad3 fp16} 8B. k3 threads gather ONE 16B line per edge.
__global__ __launch_bounds__(256) void k12a(const float* __restrict__ x,
    const float* __restrict__ W1, const float* __restrict__ as1,
    const float* __restrict__ ad1, const float* __restrict__ W2,
    unsigned short* __restrict__ Bfrag, ushort8* __restrict__ recA,
    ushort8* __restrict__ recB, ushort4v* __restrict__ recC,
    int* __restrict__ gtail, int N, int nbk1,
    const int* __restrict__ ei, int E, int NR,
    i32x2* __restrict__ queue, int* __restrict__ qcnt){
  __shared__ float vw[48];
  __shared__ int lcnt[512];
  int t = threadIdx.x;
  if ((int)blockIdx.x < nbk1){
    // ---- k1 part ----
    int gid = blockIdx.x * 256 + t;
    if (gid == 0) *gtail = 0;   // CSR allocator, consumed by k2b
    if (gid < 16384){
      int j  = gid & 7;
      int L  = (gid >> 3) & 63;
      int ct = (gid >> 9) & 3;
      int ks = gid >> 11;
      int k = ks*32 + ((L >> 4) & 3)*8 + j;
      int c = ct*16 + (L & 15);
      Bfrag[gid] = f2bf(W2[k*64 + c]);
    }
    if (t < 48){
      int side = t / 24, r = t % 24, f = r / 4, h = r % 4;
      const float* att = side ? ad1 : as1;
      float s = 0.f;
      for (int c = 0; c < 64; ++c) s += W1[f*256 + h*64 + c] * att[h*64 + c];
      vw[side*24 + f*4 + h] = s;
    }
    __syncthreads();
    int n = gid;
    if (n >= N) return;
    float xf[6];
    for (int f = 0; f < 6; ++f) xf[f] = x[n*6 + f];
    float as[4], ad[4];
    for (int h = 0; h < 4; ++h){
      float s = 0.f, d = 0.f;
      for (int f = 0; f < 6; ++f){ s += xf[f] * vw[f*4 + h]; d += xf[f] * vw[24 + f*4 + h]; }
      as[h] = s; ad[h] = d;
    }
    ushort8 va, vb;
    va[0]=f2bf(xf[0]); va[1]=f2bf(xf[1]); va[2]=f2bf(xf[2]); va[3]=f2bf(xf[3]);
    va[4]=f2bf(xf[4]); va[5]=f2bf(xf[5]); va[6]=f2h(as[0]); va[7]=f2h(as[1]);
    vb = va; vb[6]=f2h(as[2]); vb[7]=f2h(as[3]);
    ushort4v vc = {f2h(ad[0]), f2h(ad[1]), f2h(ad[2]), f2h(ad[3])};
    recA[n] = va;
    recB[n] = vb;
    recC[n] = vc;
  } else {
    // ---- k2a part (EXACT R9 logic, blk = blockIdx.x - nbk1) ----
    int blk = blockIdx.x - nbk1;
    for (int i = t; i < NR; i += 256) lcnt[i] = 0;
    __syncthreads();
    int E4 = E >> 2;
    const i32x4* s4 = (const i32x4*)ei;
    const i32x4* d4 = (const i32x4*)(ei + E);
    for (int i = blk*256 + t; i < E4; i += NB*256){
      i32x4 s = __builtin_nontemporal_load(s4 + i);
      i32x4 d = __builtin_nontemporal_load(d4 + i);
      #pragma unroll
      for (int j = 0; j < 4; ++j){
        int p = d[j] >> PARTBITS;
        int r = atomicAdd(&lcnt[p], 1);
        if (r < SEGCAP){ i32x2 v = {d[j], s[j]}; queue[((size_t)p*NB + blk)*SEGCAP + r] = v; }
      }
    }
    if (blk == 0 && t < (E & 3)){
      int e = E4*4 + t;
      int dd = ei[E + e], ss = ei[e];
      int p = dd >> PARTBITS;
      int r = atomicAdd(&lcnt[p], 1);
      if (r < SEGCAP){ i32x2 v = {dd, ss}; queue[((size_t)p*NB + blk)*SEGCAP + r] = v; }
    }
    __syncthreads();
    for (int i = t; i < NR; i += 256) qcnt[(size_t)i*NB + blk] = lcnt[i];
  }
}

// K2b (CSR compact): EXACT R14 version (replay-proven).
__global__ __launch_bounds__(1024) void k2b_build(const i32x2* __restrict__ queue,
    const int* __restrict__ qcnt, int* __restrict__ cnt,
    int* __restrict__ row_start, int* __restrict__ bucket,
    int* __restrict__ gtail){
  __shared__ int lc[BINW];
  __shared__ int lq[NB];
  __shared__ int spref[NB];
  __shared__ int npref[BINW+1];
  __shared__ int scan[BINW];
  __shared__ int lbuck[BINW*CAP];   // 48KB
  __shared__ int gbase_s;
  int t = threadIdx.x, bin = blockIdx.x;
  if (t < BINW) lc[t] = 0;
  for (int i = t; i < NB; i += 1024) lq[i] = min(qcnt[(size_t)bin*NB + i], SEGCAP);
  __syncthreads();
  if (t < 256) scan[t] = (t < NB) ? lq[t] : 0;
  __syncthreads();
  for (int off = 1; off < 256; off <<= 1){
    int v = 0;
    if (t < 256 && t >= off) v = scan[t - off];
    __syncthreads();
    if (t < 256) scan[t] += v;
    __syncthreads();
  }
  if (t < NB) spref[t] = (t == 0) ? 0 : scan[t-1];
  int V = scan[NB-1];
  __syncthreads();
  const i32x2* q = queue + (size_t)bin*NB*SEGCAP;
  for (int vi = t; vi < V; vi += 1024){
    int lo = 0, hi = NB-1;
    while (lo < hi){ int mid = (lo+hi+1) >> 1; if (spref[mid] <= vi) lo = mid; else hi = mid-1; }
    i32x2 pr = q[lo*SEGCAP + (vi - spref[lo])];
    int ld = pr.x & (BINW-1);
    int pos = atomicAdd(&lc[ld], 1);
    if (pos < CAP) lbuck[ld*CAP + pos] = pr.y;
  }
  __syncthreads();
  if (t < 256) scan[t] = min(lc[t], CAP);
  __syncthreads();
  for (int off = 1; off < 256; off <<= 1){
    int v = 0;
    if (t < 256 && t >= off) v = scan[t - off];
    __syncthreads();
    if (t < 256) scan[t] += v;
    __syncthreads();
  }
  if (t < 256) npref[t] = (t == 0) ? 0 : scan[t-1];
  if (t == 0){
    npref[BINW] = scan[BINW-1];
    gbase_s = atomicAdd(gtail, scan[BINW-1]);
  }
  __syncthreads();
  int gbase = gbase_s;
  int Vn = npref[BINW];
  for (int vi = t; vi < Vn; vi += 1024){
    int lo = 0, hi = BINW-1;
    while (lo < hi){ int mid = (lo+hi+1) >> 1; if (npref[mid] <= vi) lo = mid; else hi = mid-1; }
    bucket[gbase + vi] = lbuck[lo*CAP + (vi - npref[lo])];
  }
  if (t < BINW){
    cnt[bin*BINW + t] = min(lc[t], CAP);
    row_start[bin*BINW + t] = gbase + npref[t];
  }
}

// K3 (head-pair split): 2 threads per node. Thread hp handles heads {2hp,
// 2hp+1}, gathering ONE 16B record (recA or recB) per edge — same bytes as
// R14 but 2x TLP and half the dependent-chain depth (R14 lesson: these
// kernels are latency-chain bound, not traffic bound). No cross-lane ops.
// Output: pre-normalized af fp16, 12 per thread -> afh[n*6 + hp*3 + {0,1,2}].
__global__ __launch_bounds__(256) void k3_agg1(const ushort8* __restrict__ recA,
    const ushort8* __restrict__ recB, const ushort4v* __restrict__ recC,
    const int* __restrict__ cnt, const int* __restrict__ row_start,
    const int* __restrict__ bucket, ushort4v* __restrict__ afh, int N){
  int t2 = blockIdx.x * 256 + threadIdx.x;
  int n = t2 >> 1, hp = t2 & 1;
  if (n >= N) return;
  const ushort8* R = hp ? recB : recA;
  ushort8 v0 = R[n];
  float xf[6] = {bf2f(v0[0]), bf2f(v0[1]), bf2f(v0[2]), bf2f(v0[3]), bf2f(v0[4]), bf2f(v0[5])};
  float a_s[2] = {h2f(v0[6]), h2f(v0[7])};
  ushort4v cc = recC[n];
  float a_d[2] = {h2f(cc[hp*2]), h2f(cc[hp*2+1])};
  float acc[2][6], den[2];
  #pragma unroll
  for (int h = 0; h < 2; ++h){
    float e0 = __expf(leaky(a_s[h] + a_d[h]));   // self-loop
    den[h] = e0;
    #pragma unroll
    for (int f = 0; f < 6; ++f) acc[h][f] = e0 * xf[f];
  }
  int deg = cnt[n];
  const int* bk = bucket + row_start[n];
  int i = 0;
  for (; i + 4 <= deg; i += 4){
    int sid[4];
    #pragma unroll
    for (int j = 0; j < 4; ++j) sid[j] = bk[i+j];
    ushort8 r[4];
    #pragma unroll
    for (int j = 0; j < 4; ++j) r[j] = R[sid[j]];
    #pragma unroll
    for (int j = 0; j < 4; ++j){
      float sx[6] = {bf2f(r[j][0]), bf2f(r[j][1]), bf2f(r[j][2]),
                     bf2f(r[j][3]), bf2f(r[j][4]), bf2f(r[j][5])};
      float sa[2] = {h2f(r[j][6]), h2f(r[j][7])};
      #pragma unroll
      for (int h = 0; h < 2; ++h){
        float e = __expf(leaky(sa[h] + a_d[h]));
        den[h] += e;
        #pragma unroll
        for (int f = 0; f < 6; ++f) acc[h][f] += e * sx[f];
      }
    }
  }
  for (; i < deg; ++i){
    ushort8 r = R[bk[i]];
    float sx[6] = {bf2f(r[0]), bf2f(r[1]), bf2f(r[2]), bf2f(r[3]), bf2f(r[4]), bf2f(r[5])};
    float sa[2] = {h2f(r[6]), h2f(r[7])};
    #pragma unroll
    for (int h = 0; h < 2; ++h){
      float e = __expf(leaky(sa[h] + a_d[h]));
      den[h] += e;
      #pragma unroll
      for (int f = 0; f < 6; ++f) acc[h][f] += e * sx[f];
    }
  }
  float d0 = 1.f / den[0], d1 = 1.f / den[1];
  ushort4v o0 = {f2h(acc[0][0]*d0), f2h(acc[0][1]*d0), f2h(acc[0][2]*d0), f2h(acc[0][3]*d0)};
  ushort4v o1 = {f2h(acc[0][4]*d0), f2h(acc[0][5]*d0), f2h(acc[1][0]*d1), f2h(acc[1][1]*d1)};
  ushort4v o2 = {f2h(acc[1][2]*d1), f2h(acc[1][3]*d1), f2h(acc[1][4]*d1), f2h(acc[1][5]*d1)};
  size_t ob = (size_t)n*6 + hp*3;
  afh[ob + 0] = o0;
  afh[ob + 1] = o1;
  afh[ob + 2] = o2;
}

// K4 (MFMA + LDS staging, R13-proven): af now pre-normalized fp16 (48B/node,
// was 128B fp32 + reciprocal). a2 split into a2s/a2d for k5's 4B gathers.
__global__ __launch_bounds__(256) void k4_mfma(
    const ushort4v* __restrict__ afh, const float* __restrict__ W1,
    const float* __restrict__ b1, const unsigned short* __restrict__ Bfrag,
    const float* __restrict__ as2v, const float* __restrict__ ad2v,
    unsigned short* __restrict__ h2h, float* __restrict__ a2s,
    float* __restrict__ a2d, int N){
  __shared__ float w1s[6*256];     // 6KB
  __shared__ float b1s[256];       // 1KB
  __shared__ ushort8 bfs[2048];    // 32KB
  int t = threadIdx.x;
  {
    const float4* w1g = (const float4*)W1;
    float4* w1l = (float4*)w1s;
    for (int i = t; i < 384; i += 256) w1l[i] = w1g[i];
    if (t < 64) ((float4*)b1s)[t] = ((const float4*)b1)[t];
    const ushort8* bfg = (const ushort8*)Bfrag;
    #pragma unroll
    for (int i = 0; i < 8; ++i) bfs[t + 256*i] = bfg[t + 256*i];
  }
  int L = t & 63;
  int w = t >> 6;
  int base = blockIdx.x * 64;
  int m = L & 15;
  int quad = L >> 4;
  int na = base + w*16 + m;
  int nc = min(na, N-1);
  float af[24];
  {
    const ushort8* A8 = (const ushort8*)(afh + (size_t)nc*6);  // 48B, 16B-aligned
    ushort8 u0 = A8[0], u1 = A8[1], u2 = A8[2];
    #pragma unroll
    for (int j = 0; j < 8; ++j) af[j] = h2f(u0[j]);
    #pragma unroll
    for (int j = 0; j < 8; ++j) af[8+j] = h2f(u1[j]);
    #pragma unroll
    for (int j = 0; j < 8; ++j) af[16+j] = h2f(u2[j]);
  }
  f32x4 acc[4];
  #pragma unroll
  for (int ct = 0; ct < 4; ++ct) acc[ct] = (f32x4){0.f, 0.f, 0.f, 0.f};
  __syncthreads();

  #pragma unroll
  for (int ks = 0; ks < 8; ++ks){
    int kb = ks*32 + quad*8;
    int kc = kb >> 6;
    const float* afk = af + kc*6;
    float4 bb0 = *(const float4*)(b1s + kb);
    float4 bb1 = *(const float4*)(b1s + kb + 4);
    float s0=bb0.x, s1=bb0.y, s2=bb0.z, s3=bb0.w;
    float s4=bb1.x, s5=bb1.y, s6=bb1.z, s7=bb1.w;
    #pragma unroll
    for (int f = 0; f < 6; ++f){
      float a = afk[f];
      float4 w0 = *(const float4*)(w1s + f*256 + kb);
      float4 w1 = *(const float4*)(w1s + f*256 + kb + 4);
      s0 += a*w0.x; s1 += a*w0.y; s2 += a*w0.z; s3 += a*w0.w;
      s4 += a*w1.x; s5 += a*w1.y; s6 += a*w1.z; s7 += a*w1.w;
    }
    ushort8 ap;
    ap[0]=f2bf(eluf(s0)); ap[1]=f2bf(eluf(s1)); ap[2]=f2bf(eluf(s2)); ap[3]=f2bf(eluf(s3));
    ap[4]=f2bf(eluf(s4)); ap[5]=f2bf(eluf(s5)); ap[6]=f2bf(eluf(s6)); ap[7]=f2bf(eluf(s7));
    bf16x8 av = __builtin_bit_cast(bf16x8, ap);
    #pragma unroll
    for (int ct = 0; ct < 4; ++ct){
      bf16x8 bv = __builtin_bit_cast(bf16x8, bfs[(ks*4 + ct)*64 + L]);
      acc[ct] = __builtin_amdgcn_mfma_f32_16x16x32_bf16(av, bv, acc[ct], 0, 0, 0);
    }
  }

  float asv[4], adv[4];
  #pragma unroll
  for (int ct = 0; ct < 4; ++ct){ asv[ct] = as2v[ct*16 + m]; adv[ct] = ad2v[ct*16 + m]; }
  float ps[4] = {0,0,0,0}, pd[4] = {0,0,0,0};
  #pragma unroll
  for (int ct = 0; ct < 4; ++ct)
    #pragma unroll
    for (int r = 0; r < 4; ++r){
      ps[r] += acc[ct][r] * asv[ct];
      pd[r] += acc[ct][r] * adv[ct];
    }
  #pragma unroll
  for (int r = 0; r < 4; ++r){
    int nr = base + w*16 + quad*4 + r;
    if (nr < N){
      #pragma unroll
      for (int ct = 0; ct < 4; ++ct)
        h2h[(size_t)nr*64 + ct*16 + m] = f2h(acc[ct][r]);
    }
  }
  #pragma unroll
  for (int mask = 1; mask <= 8; mask <<= 1){
    #pragma unroll
    for (int r = 0; r < 4; ++r){
      ps[r] += __shfl_xor(ps[r], mask, 64);
      pd[r] += __shfl_xor(pd[r], mask, 64);
    }
  }
  if (m == 0){
    #pragma unroll
    for (int r = 0; r < 4; ++r){
      int nr = base + w*16 + quad*4 + r;
      if (nr < N){ a2s[nr] = ps[r]; a2d[nr] = pd[r]; }
    }
  }
}

// K5: layer-2 aggregation only for drone dsts (first ND) + elu + MLP head.
// fp16 h2 gathers; a2s (4B) per-edge gathers; bucket CSR. R14 body otherwise.
__global__ __launch_bounds__(256) void k5_out(
    const unsigned short* __restrict__ h2h, const float* __restrict__ a2s,
    const float* __restrict__ a2d, const int* __restrict__ cnt,
    const int* __restrict__ row_start, const int* __restrict__ bucket,
    const float* __restrict__ b2, const float* __restrict__ fc1w,
    const float* __restrict__ fc1b, const float* __restrict__ fc2w,
    const float* __restrict__ fc2b, float* __restrict__ out, int ND){
  __shared__ float hb[4][64];
  int lane = threadIdx.x & 63;
  int w = threadIdx.x >> 6;
  int n = blockIdx.x * 4 + w;
  if (n >= ND) return;
  float adv = a2d[n];
  float e0 = __expf(leaky(a2s[n] + adv));
  float den = e0;
  float acc = e0 * h2f(h2h[(size_t)n*64 + lane]);
  int deg = cnt[n];
  const int* bk = bucket + row_start[n];
  int i = 0;
  for (; i + 4 <= deg; i += 4){
    int sid[4];
    #pragma unroll
    for (int j = 0; j < 4; ++j) sid[j] = bk[i+j];
    float av[4]; unsigned short hv4[4];
    #pragma unroll
    for (int j = 0; j < 4; ++j){
      av[j] = a2s[sid[j]];
      hv4[j] = h2h[(size_t)sid[j]*64 + lane];
    }
    #pragma unroll
    for (int j = 0; j < 4; ++j){
      float e = __expf(leaky(av[j] + adv));
      den += e;
      acc += e * h2f(hv4[j]);
    }
  }
  for (; i < deg; ++i){
    int s = bk[i];
    float e = __expf(leaky(a2s[s] + adv));
    den += e;
    acc += e * h2f(h2h[(size_t)s*64 + lane]);
  }
  float hv = eluf(acc / den + b2[lane]);
  hb[w][lane] = hv;               // wave-local LDS (lockstep wave64)
  float t1 = fc1b[lane];
  for (int k = 0; k < 64; ++k) t1 += hb[w][k] * fc1w[k*64 + lane];
  t1 = fmaxf(t1, 0.f);
  float p0 = t1 * fc2w[lane*2 + 0];
  float p1 = t1 * fc2w[lane*2 + 1];
  for (int o = 32; o > 0; o >>= 1){
    p0 += __shfl_down(p0, o, 64);
    p1 += __shfl_down(p1, o, 64);
  }
  if (lane == 0){
    out[n*2 + 0] = tanhf(p0 + fc2b[0]) * 2.f;
    out[n*2 + 1] = tanhf(p1 + fc2b[1]) * 2.f;
  }
}

extern "C" void kernel_launch(void* const* d_in, const int* in_sizes, int n_in,
                              void* d_out, int out_size, void* d_ws, size_t ws_size,
                              hipStream_t stream){
  const float* x    = (const float*)d_in[0];
  const int*   ei   = (const int*)d_in[1];    // harness passes integers as int32
  const float* W1   = (const float*)d_in[3];
  const float* as1  = (const float*)d_in[4];
  const float* ad1  = (const float*)d_in[5];
  const float* b1   = (const float*)d_in[6];
  const float* W2   = (const float*)d_in[7];
  const float* as2  = (const float*)d_in[8];
  const float* ad2  = (const float*)d_in[9];
  const float* b2   = (const float*)d_in[10];
  const float* fc1w = (const float*)d_in[11];
  const float* fc1b = (const float*)d_in[12];
  const float* fc2w = (const float*)d_in[13];
  const float* fc2b = (const float*)d_in[14];
  float* out = (float*)d_out;

  int N  = in_sizes[0] / 6;
  int E  = in_sizes[1] / 2;
  int ND = out_size / 2;
  int NR = (N + BINW - 1) >> PARTBITS;   // number of dst bins
  int nbk1 = (N + 255) / 256;

  char* p = (char*)d_ws;
  auto alloc = [&](size_t bytes){ void* r = (void*)p; p += (bytes + 255) & ~(size_t)255; return r; };
  int*            cnt    = (int*)           alloc((size_t)NR * BINW * 4);
  int*            rowst  = (int*)           alloc((size_t)NR * BINW * 4);
  int*            bucket = (int*)           alloc(((size_t)E + 1024) * 4);   // CSR
  ushort8*        recA   = (ushort8*)       alloc((size_t)N * 16);
  ushort8*        recB   = (ushort8*)       alloc((size_t)N * 16);
  ushort4v*       recC   = (ushort4v*)      alloc((size_t)N * 8);
  ushort4v*       afh    = (ushort4v*)      alloc((size_t)N * 48);
  unsigned short* h2h    = (unsigned short*)alloc((size_t)N * 128);
  float*          a2s    = (float*)         alloc((size_t)N * 4);
  float*          a2d    = (float*)         alloc((size_t)N * 4);
  unsigned short* Bfrag  = (unsigned short*)alloc(16384 * 2);
  i32x2*          queue  = (i32x2*)         alloc((size_t)NR * NB * SEGCAP * 8);
  int*            qcnt   = (int*)           alloc((size_t)NR * NB * 4);
  int*            gtail  = (int*)           alloc(256);

  size_t needed = (size_t)(p - (char*)d_ws);
  if (needed > ws_size) return;   // clean fail instead of GPU fault

  k12a<<<nbk1 + NB, 256, 0, stream>>>(x, W1, as1, ad1, W2, Bfrag, recA, recB,
                                      recC, gtail, N, nbk1, ei, E, NR, queue, qcnt);
  k2b_build<<<NR, 1024, 0, stream>>>(queue, qcnt, cnt, rowst, bucket, gtail);
  k3_agg1<<<(2*N + 255)/256, 256, 0, stream>>>(recA, recB, recC, cnt, rowst,
                                               bucket, afh, N);
  k4_mfma<<<(N + 63)/64, 256, 0, stream>>>(afh, W1, b1, Bfrag, as2, ad2,
                                           h2h, a2s, a2d, N);
  k5_out<<<(ND + 3)/4, 256, 0, stream>>>(h2h, a2s, a2d, cnt, rowst, bucket, b2,
                                         fc1w, fc1b, fc2w, fc2b, out, ND);
}

// Round 16
// 176.399 us; speedup vs baseline: 1.1019x; 1.0883x over previous
//
#include <hip/hip_runtime.h>
#include <hip/hip_fp16.h>
#include <math.h>

#define CAP 48       // max bucketed in-degree; Poisson(16), P(deg>=48) ~ 8e-11/node
#define PARTBITS 8   // 256 dsts per bin
#define BINW 256
#define NB 240       // routing blocks
#define SEGCAP 48    // per-(bin,block) queue segment; mean 17, 7.5 sigma

typedef float f32x4 __attribute__((ext_vector_type(4)));
typedef __bf16 bf16x8 __attribute__((ext_vector_type(8)));
typedef unsigned short ushort8 __attribute__((ext_vector_type(8)));
typedef unsigned short ushort4v __attribute__((ext_vector_type(4)));
typedef int i32x4 __attribute__((ext_vector_type(4)));
typedef int i32x2 __attribute__((ext_vector_type(2)));

__device__ __forceinline__ float leaky(float x){ return x > 0.f ? x : 0.2f * x; }
__device__ __forceinline__ float eluf(float x){ return x > 0.f ? x : __expf(x) - 1.f; }
__device__ __forceinline__ unsigned short f2bf(float f){  // RNE float->bf16
  unsigned u = __float_as_uint(f);
  u += 0x7FFF + ((u >> 16) & 1);
  return (unsigned short)(u >> 16);
}
__device__ __forceinline__ float bf2f(unsigned short u){
  return __uint_as_float(((unsigned)u) << 16);
}
__device__ __forceinline__ unsigned short f2h(float f){
  return __half_as_ushort(__float2half(f));
}
__device__ __forceinline__ float h2f(unsigned short u){
  return __half2float(__ushort_as_half(u));
}

// K12a: fused k1 (node records + Bfrag prepack) and k2a (edge routing).
// EXACT R15 version (replay-proven).
__global__ __launch_bounds__(256) void k12a(const float* __restrict__ x,
    const float* __restrict__ W1, const float* __restrict__ as1,
    const float* __restrict__ ad1, const float* __restrict__ W2,
    unsigned short* __restrict__ Bfrag, ushort8* __restrict__ recA,
    ushort8* __restrict__ recB, ushort4v* __restrict__ recC,
    int* __restrict__ gtail, int N, int nbk1,
    const int* __restrict__ ei, int E, int NR,
    i32x2* __restrict__ queue, int* __restrict__ qcnt){
  __shared__ float vw[48];
  __shared__ int lcnt[512];
  int t = threadIdx.x;
  if ((int)blockIdx.x < nbk1){
    int gid = blockIdx.x * 256 + t;
    if (gid == 0) *gtail = 0;   // CSR allocator, consumed by k2b3
    if (gid < 16384){
      int j  = gid & 7;
      int L  = (gid >> 3) & 63;
      int ct = (gid >> 9) & 3;
      int ks = gid >> 11;
      int k = ks*32 + ((L >> 4) & 3)*8 + j;
      int c = ct*16 + (L & 15);
      Bfrag[gid] = f2bf(W2[k*64 + c]);
    }
    if (t < 48){
      int side = t / 24, r = t % 24, f = r / 4, h = r % 4;
      const float* att = side ? ad1 : as1;
      float s = 0.f;
      for (int c = 0; c < 64; ++c) s += W1[f*256 + h*64 + c] * att[h*64 + c];
      vw[side*24 + f*4 + h] = s;
    }
    __syncthreads();
    int n = gid;
    if (n >= N) return;
    float xf[6];
    for (int f = 0; f < 6; ++f) xf[f] = x[n*6 + f];
    float as[4], ad[4];
    for (int h = 0; h < 4; ++h){
      float s = 0.f, d = 0.f;
      for (int f = 0; f < 6; ++f){ s += xf[f] * vw[f*4 + h]; d += xf[f] * vw[24 + f*4 + h]; }
      as[h] = s; ad[h] = d;
    }
    ushort8 va, vb;
    va[0]=f2bf(xf[0]); va[1]=f2bf(xf[1]); va[2]=f2bf(xf[2]); va[3]=f2bf(xf[3]);
    va[4]=f2bf(xf[4]); va[5]=f2bf(xf[5]); va[6]=f2h(as[0]); va[7]=f2h(as[1]);
    vb = va; vb[6]=f2h(as[2]); vb[7]=f2h(as[3]);
    ushort4v vc = {f2h(ad[0]), f2h(ad[1]), f2h(ad[2]), f2h(ad[3])};
    recA[n] = va;
    recB[n] = vb;
    recC[n] = vc;
  } else {
    int blk = blockIdx.x - nbk1;
    for (int i = t; i < NR; i += 256) lcnt[i] = 0;
    __syncthreads();
    int E4 = E >> 2;
    const i32x4* s4 = (const i32x4*)ei;
    const i32x4* d4 = (const i32x4*)(ei + E);
    for (int i = blk*256 + t; i < E4; i += NB*256){
      i32x4 s = __builtin_nontemporal_load(s4 + i);
      i32x4 d = __builtin_nontemporal_load(d4 + i);
      #pragma unroll
      for (int j = 0; j < 4; ++j){
        int p = d[j] >> PARTBITS;
        int r = atomicAdd(&lcnt[p], 1);
        if (r < SEGCAP){ i32x2 v = {d[j], s[j]}; queue[((size_t)p*NB + blk)*SEGCAP + r] = v; }
      }
    }
    if (blk == 0 && t < (E & 3)){
      int e = E4*4 + t;
      int dd = ei[E + e], ss = ei[e];
      int p = dd >> PARTBITS;
      int r = atomicAdd(&lcnt[p], 1);
      if (r < SEGCAP){ i32x2 v = {dd, ss}; queue[((size_t)p*NB + blk)*SEGCAP + r] = v; }
    }
    __syncthreads();
    for (int i = t; i < NR; i += 256) qcnt[(size_t)i*NB + blk] = lcnt[i];
  }
}

// K2b3 (fused bucket-build + layer-1 aggregation): one block per bin.
// R15 plateau evidence: every kernel <43µs; remaining cost is the CSR global
// round-trip (k2b writes 11MB that k3 immediately re-reads) + a dispatch gap.
// Phase A: R14's lbuck build (exact). Phase B: CSR write-out ONLY for the
// drone bins k5 reads (bin < nd_bins; ~0.7MB vs 11MB). Phase C: R15's k3
// body, 2 threads/node, bucket read from LDS. Block-uniform branches only.
__global__ __launch_bounds__(1024) void k2b3(const i32x2* __restrict__ queue,
    const int* __restrict__ qcnt,
    const ushort8* __restrict__ recA, const ushort8* __restrict__ recB,
    const ushort4v* __restrict__ recC,
    int* __restrict__ cnt, int* __restrict__ row_start,
    int* __restrict__ bucket, int* __restrict__ gtail,
    ushort4v* __restrict__ afh, int nd_bins, int N){
  __shared__ int lc[BINW];
  __shared__ int lq[NB];
  __shared__ int spref[NB];
  __shared__ int npref[BINW+1];
  __shared__ int scan[BINW];
  __shared__ int lbuck[BINW*CAP];   // 48KB
  __shared__ int gbase_s;
  int t = threadIdx.x, bin = blockIdx.x;
  // ---- phase A: R14 lbuck build (exact) ----
  if (t < BINW) lc[t] = 0;
  for (int i = t; i < NB; i += 1024) lq[i] = min(qcnt[(size_t)bin*NB + i], SEGCAP);
  __syncthreads();
  if (t < 256) scan[t] = (t < NB) ? lq[t] : 0;
  __syncthreads();
  for (int off = 1; off < 256; off <<= 1){
    int v = 0;
    if (t < 256 && t >= off) v = scan[t - off];
    __syncthreads();
    if (t < 256) scan[t] += v;
    __syncthreads();
  }
  if (t < NB) spref[t] = (t == 0) ? 0 : scan[t-1];
  int V = scan[NB-1];
  __syncthreads();
  const i32x2* q = queue + (size_t)bin*NB*SEGCAP;
  for (int vi = t; vi < V; vi += 1024){
    int lo = 0, hi = NB-1;
    while (lo < hi){ int mid = (lo+hi+1) >> 1; if (spref[mid] <= vi) lo = mid; else hi = mid-1; }
    i32x2 pr = q[lo*SEGCAP + (vi - spref[lo])];
    int ld = pr.x & (BINW-1);
    int pos = atomicAdd(&lc[ld], 1);
    if (pos < CAP) lbuck[ld*CAP + pos] = pr.y;
  }
  __syncthreads();
  // ---- phase B: CSR write-out, drone bins only (block-uniform branch) ----
  if (bin < nd_bins){
    if (t < 256) scan[t] = min(lc[t], CAP);
    __syncthreads();
    for (int off = 1; off < 256; off <<= 1){
      int v = 0;
      if (t < 256 && t >= off) v = scan[t - off];
      __syncthreads();
      if (t < 256) scan[t] += v;
      __syncthreads();
    }
    if (t < 256) npref[t] = (t == 0) ? 0 : scan[t-1];
    if (t == 0){
      npref[BINW] = scan[BINW-1];
      gbase_s = atomicAdd(gtail, scan[BINW-1]);
    }
    __syncthreads();
    int gbase = gbase_s;
    int Vn = npref[BINW];
    for (int vi = t; vi < Vn; vi += 1024){
      int lo = 0, hi = BINW-1;
      while (lo < hi){ int mid = (lo+hi+1) >> 1; if (npref[mid] <= vi) lo = mid; else hi = mid-1; }
      bucket[gbase + vi] = lbuck[lo*CAP + (vi - npref[lo])];
    }
    if (t < BINW){
      cnt[bin*BINW + t] = min(lc[t], CAP);
      row_start[bin*BINW + t] = gbase + npref[t];
    }
    __syncthreads();
  }
  // ---- phase C: R15 k3 aggregation, 2 threads/node, bucket from LDS ----
  if (t < 512){
    int dl = t >> 1, hp = t & 1;
    int n = bin*BINW + dl;
    if (n < N){
      const ushort8* R = hp ? recB : recA;
      ushort8 v0 = R[n];
      float xf[6] = {bf2f(v0[0]), bf2f(v0[1]), bf2f(v0[2]), bf2f(v0[3]), bf2f(v0[4]), bf2f(v0[5])};
      float a_s[2] = {h2f(v0[6]), h2f(v0[7])};
      ushort4v cc = recC[n];
      float a_d[2] = {h2f(cc[hp*2]), h2f(cc[hp*2+1])};
      float acc[2][6], den[2];
      #pragma unroll
      for (int h = 0; h < 2; ++h){
        float e0 = __expf(leaky(a_s[h] + a_d[h]));   // self-loop
        den[h] = e0;
        #pragma unroll
        for (int f = 0; f < 6; ++f) acc[h][f] = e0 * xf[f];
      }
      int deg = min(lc[dl], CAP);
      const int* bk = &lbuck[dl*CAP];
      int i = 0;
      for (; i + 4 <= deg; i += 4){
        int sid[4];
        #pragma unroll
        for (int j = 0; j < 4; ++j) sid[j] = bk[i+j];
        ushort8 r[4];
        #pragma unroll
        for (int j = 0; j < 4; ++j) r[j] = R[sid[j]];
        #pragma unroll
        for (int j = 0; j < 4; ++j){
          float sx[6] = {bf2f(r[j][0]), bf2f(r[j][1]), bf2f(r[j][2]),
                         bf2f(r[j][3]), bf2f(r[j][4]), bf2f(r[j][5])};
          float sa[2] = {h2f(r[j][6]), h2f(r[j][7])};
          #pragma unroll
          for (int h = 0; h < 2; ++h){
            float e = __expf(leaky(sa[h] + a_d[h]));
            den[h] += e;
            #pragma unroll
            for (int f = 0; f < 6; ++f) acc[h][f] += e * sx[f];
          }
        }
      }
      for (; i < deg; ++i){
        ushort8 r = R[bk[i]];
        float sx[6] = {bf2f(r[0]), bf2f(r[1]), bf2f(r[2]), bf2f(r[3]), bf2f(r[4]), bf2f(r[5])};
        float sa[2] = {h2f(r[6]), h2f(r[7])};
        #pragma unroll
        for (int h = 0; h < 2; ++h){
          float e = __expf(leaky(sa[h] + a_d[h]));
          den[h] += e;
          #pragma unroll
          for (int f = 0; f < 6; ++f) acc[h][f] += e * sx[f];
        }
      }
      float d0 = 1.f / den[0], d1 = 1.f / den[1];
      ushort4v o0 = {f2h(acc[0][0]*d0), f2h(acc[0][1]*d0), f2h(acc[0][2]*d0), f2h(acc[0][3]*d0)};
      ushort4v o1 = {f2h(acc[0][4]*d0), f2h(acc[0][5]*d0), f2h(acc[1][0]*d1), f2h(acc[1][1]*d1)};
      ushort4v o2 = {f2h(acc[1][2]*d1), f2h(acc[1][3]*d1), f2h(acc[1][4]*d1), f2h(acc[1][5]*d1)};
      size_t ob = (size_t)n*6 + hp*3;
      afh[ob + 0] = o0;
      afh[ob + 1] = o1;
      afh[ob + 2] = o2;
    }
  }
}

// K4 (MFMA + LDS staging): EXACT R15 version.
__global__ __launch_bounds__(256) void k4_mfma(
    const ushort4v* __restrict__ afh, const float* __restrict__ W1,
    const float* __restrict__ b1, const unsigned short* __restrict__ Bfrag,
    const float* __restrict__ as2v, const float* __restrict__ ad2v,
    unsigned short* __restrict__ h2h, float* __restrict__ a2s,
    float* __restrict__ a2d, int N){
  __shared__ float w1s[6*256];     // 6KB
  __shared__ float b1s[256];       // 1KB
  __shared__ ushort8 bfs[2048];    // 32KB
  int t = threadIdx.x;
  {
    const float4* w1g = (const float4*)W1;
    float4* w1l = (float4*)w1s;
    for (int i = t; i < 384; i += 256) w1l[i] = w1g[i];
    if (t < 64) ((float4*)b1s)[t] = ((const float4*)b1)[t];
    const ushort8* bfg = (const ushort8*)Bfrag;
    #pragma unroll
    for (int i = 0; i < 8; ++i) bfs[t + 256*i] = bfg[t + 256*i];
  }
  int L = t & 63;
  int w = t >> 6;
  int base = blockIdx.x * 64;
  int m = L & 15;
  int quad = L >> 4;
  int na = base + w*16 + m;
  int nc = min(na, N-1);
  float af[24];
  {
    const ushort8* A8 = (const ushort8*)(afh + (size_t)nc*6);  // 48B, 16B-aligned
    ushort8 u0 = A8[0], u1 = A8[1], u2 = A8[2];
    #pragma unroll
    for (int j = 0; j < 8; ++j) af[j] = h2f(u0[j]);
    #pragma unroll
    for (int j = 0; j < 8; ++j) af[8+j] = h2f(u1[j]);
    #pragma unroll
    for (int j = 0; j < 8; ++j) af[16+j] = h2f(u2[j]);
  }
  f32x4 acc[4];
  #pragma unroll
  for (int ct = 0; ct < 4; ++ct) acc[ct] = (f32x4){0.f, 0.f, 0.f, 0.f};
  __syncthreads();

  #pragma unroll
  for (int ks = 0; ks < 8; ++ks){
    int kb = ks*32 + quad*8;
    int kc = kb >> 6;
    const float* afk = af + kc*6;
    float4 bb0 = *(const float4*)(b1s + kb);
    float4 bb1 = *(const float4*)(b1s + kb + 4);
    float s0=bb0.x, s1=bb0.y, s2=bb0.z, s3=bb0.w;
    float s4=bb1.x, s5=bb1.y, s6=bb1.z, s7=bb1.w;
    #pragma unroll
    for (int f = 0; f < 6; ++f){
      float a = afk[f];
      float4 w0 = *(const float4*)(w1s + f*256 + kb);
      float4 w1 = *(const float4*)(w1s + f*256 + kb + 4);
      s0 += a*w0.x; s1 += a*w0.y; s2 += a*w0.z; s3 += a*w0.w;
      s4 += a*w1.x; s5 += a*w1.y; s6 += a*w1.z; s7 += a*w1.w;
    }
    ushort8 ap;
    ap[0]=f2bf(eluf(s0)); ap[1]=f2bf(eluf(s1)); ap[2]=f2bf(eluf(s2)); ap[3]=f2bf(eluf(s3));
    ap[4]=f2bf(eluf(s4)); ap[5]=f2bf(eluf(s5)); ap[6]=f2bf(eluf(s6)); ap[7]=f2bf(eluf(s7));
    bf16x8 av = __builtin_bit_cast(bf16x8, ap);
    #pragma unroll
    for (int ct = 0; ct < 4; ++ct){
      bf16x8 bv = __builtin_bit_cast(bf16x8, bfs[(ks*4 + ct)*64 + L]);
      acc[ct] = __builtin_amdgcn_mfma_f32_16x16x32_bf16(av, bv, acc[ct], 0, 0, 0);
    }
  }

  float asv[4], adv[4];
  #pragma unroll
  for (int ct = 0; ct < 4; ++ct){ asv[ct] = as2v[ct*16 + m]; adv[ct] = ad2v[ct*16 + m]; }
  float ps[4] = {0,0,0,0}, pd[4] = {0,0,0,0};
  #pragma unroll
  for (int ct = 0; ct < 4; ++ct)
    #pragma unroll
    for (int r = 0; r < 4; ++r){
      ps[r] += acc[ct][r] * asv[ct];
      pd[r] += acc[ct][r] * adv[ct];
    }
  #pragma unroll
  for (int r = 0; r < 4; ++r){
    int nr = base + w*16 + quad*4 + r;
    if (nr < N){
      #pragma unroll
      for (int ct = 0; ct < 4; ++ct)
        h2h[(size_t)nr*64 + ct*16 + m] = f2h(acc[ct][r]);
    }
  }
  #pragma unroll
  for (int mask = 1; mask <= 8; mask <<= 1){
    #pragma unroll
    for (int r = 0; r < 4; ++r){
      ps[r] += __shfl_xor(ps[r], mask, 64);
      pd[r] += __shfl_xor(pd[r], mask, 64);
    }
  }
  if (m == 0){
    #pragma unroll
    for (int r = 0; r < 4; ++r){
      int nr = base + w*16 + quad*4 + r;
      if (nr < N){ a2s[nr] = ps[r]; a2d[nr] = pd[r]; }
    }
  }
}

// K5: layer-2 aggregation only for drone dsts (first ND) + elu + MLP head.
// EXACT R15 version.
__global__ __launch_bounds__(256) void k5_out(
    const unsigned short* __restrict__ h2h, const float* __restrict__ a2s,
    const float* __restrict__ a2d, const int* __restrict__ cnt,
    const int* __restrict__ row_start, const int* __restrict__ bucket,
    const float* __restrict__ b2, const float* __restrict__ fc1w,
    const float* __restrict__ fc1b, const float* __restrict__ fc2w,
    const float* __restrict__ fc2b, float* __restrict__ out, int ND){
  __shared__ float hb[4][64];
  int lane = threadIdx.x & 63;
  int w = threadIdx.x >> 6;
  int n = blockIdx.x * 4 + w;
  if (n >= ND) return;
  float adv = a2d[n];
  float e0 = __expf(leaky(a2s[n] + adv));
  float den = e0;
  float acc = e0 * h2f(h2h[(size_t)n*64 + lane]);
  int deg = cnt[n];
  const int* bk = bucket + row_start[n];
  int i = 0;
  for (; i + 4 <= deg; i += 4){
    int sid[4];
    #pragma unroll
    for (int j = 0; j < 4; ++j) sid[j] = bk[i+j];
    float av[4]; unsigned short hv4[4];
    #pragma unroll
    for (int j = 0; j < 4; ++j){
      av[j] = a2s[sid[j]];
      hv4[j] = h2h[(size_t)sid[j]*64 + lane];
    }
    #pragma unroll
    for (int j = 0; j < 4; ++j){
      float e = __expf(leaky(av[j] + adv));
      den += e;
      acc += e * h2f(hv4[j]);
    }
  }
  for (; i < deg; ++i){
    int s = bk[i];
    float e = __expf(leaky(a2s[s] + adv));
    den += e;
    acc += e * h2f(h2h[(size_t)s*64 + lane]);
  }
  float hv = eluf(acc / den + b2[lane]);
  hb[w][lane] = hv;               // wave-local LDS (lockstep wave64)
  float t1 = fc1b[lane];
  for (int k = 0; k < 64; ++k) t1 += hb[w][k] * fc1w[k*64 + lane];
  t1 = fmaxf(t1, 0.f);
  float p0 = t1 * fc2w[lane*2 + 0];
  float p1 = t1 * fc2w[lane*2 + 1];
  for (int o = 32; o > 0; o >>= 1){
    p0 += __shfl_down(p0, o, 64);
    p1 += __shfl_down(p1, o, 64);
  }
  if (lane == 0){
    out[n*2 + 0] = tanhf(p0 + fc2b[0]) * 2.f;
    out[n*2 + 1] = tanhf(p1 + fc2b[1]) * 2.f;
  }
}

extern "C" void kernel_launch(void* const* d_in, const int* in_sizes, int n_in,
                              void* d_out, int out_size, void* d_ws, size_t ws_size,
                              hipStream_t stream){
  const float* x    = (const float*)d_in[0];
  const int*   ei   = (const int*)d_in[1];    // harness passes integers as int32
  const float* W1   = (const float*)d_in[3];
  const float* as1  = (const float*)d_in[4];
  const float* ad1  = (const float*)d_in[5];
  const float* b1   = (const float*)d_in[6];
  const float* W2   = (const float*)d_in[7];
  const float* as2  = (const float*)d_in[8];
  const float* ad2  = (const float*)d_in[9];
  const float* b2   = (const float*)d_in[10];
  const float* fc1w = (const float*)d_in[11];
  const float* fc1b = (const float*)d_in[12];
  const float* fc2w = (const float*)d_in[13];
  const float* fc2b = (const float*)d_in[14];
  float* out = (float*)d_out;

  int N  = in_sizes[0] / 6;
  int E  = in_sizes[1] / 2;
  int ND = out_size / 2;
  int NR = (N + BINW - 1) >> PARTBITS;   // number of dst bins
  int nd_bins = (ND + BINW - 1) / BINW;  // bins containing drone dsts (k5)
  int nbk1 = (N + 255) / 256;

  char* p = (char*)d_ws;
  auto alloc = [&](size_t bytes){ void* r = (void*)p; p += (bytes + 255) & ~(size_t)255; return r; };
  int*            cnt    = (int*)           alloc((size_t)NR * BINW * 4);
  int*            rowst  = (int*)           alloc((size_t)NR * BINW * 4);
  int*            bucket = (int*)           alloc(((size_t)E + 1024) * 4);   // CSR (drone bins only)
  ushort8*        recA   = (ushort8*)       alloc((size_t)N * 16);
  ushort8*        recB   = (ushort8*)       alloc((size_t)N * 16);
  ushort4v*       recC   = (ushort4v*)      alloc((size_t)N * 8);
  ushort4v*       afh    = (ushort4v*)      alloc((size_t)N * 48);
  unsigned short* h2h    = (unsigned short*)alloc((size_t)N * 128);
  float*          a2s    = (float*)         alloc((size_t)N * 4);
  float*          a2d    = (float*)         alloc((size_t)N * 4);
  unsigned short* Bfrag  = (unsigned short*)alloc(16384 * 2);
  i32x2*          queue  = (i32x2*)         alloc((size_t)NR * NB * SEGCAP * 8);
  int*            qcnt   = (int*)           alloc((size_t)NR * NB * 4);
  int*            gtail  = (int*)           alloc(256);

  size_t needed = (size_t)(p - (char*)d_ws);
  if (needed > ws_size) return;   // clean fail instead of GPU fault

  k12a<<<nbk1 + NB, 256, 0, stream>>>(x, W1, as1, ad1, W2, Bfrag, recA, recB,
                                      recC, gtail, N, nbk1, ei, E, NR, queue, qcnt);
  k2b3<<<NR, 1024, 0, stream>>>(queue, qcnt, recA, recB, recC,
                                cnt, rowst, bucket, gtail, afh, nd_bins, N);
  k4_mfma<<<(N + 63)/64, 256, 0, stream>>>(afh, W1, b1, Bfrag, as2, ad2,
                                           h2h, a2s, a2d, N);
  k5_out<<<(ND + 3)/4, 256, 0, stream>>>(h2h, a2s, a2d, cnt, rowst, bucket, b2,
                                         fc1w, fc1b, fc2w, fc2b, out, ND);
}